// Round 2
// baseline (4955.487 us; speedup 1.0000x reference)
//
#include <hip/hip_runtime.h>
#include <cstddef>

// Problem constants (from reference): N=100000, E=800000, F=H=128, C=10, G=512
#define HD 128

static __device__ __forceinline__ void atomAddF(float* p, float v) {
    (void)__hip_atomic_fetch_add(p, v, __ATOMIC_RELAXED, __HIP_MEMORY_SCOPE_AGENT);
}

// deg[i] = 1 (self loop)
__global__ void k_fill1(float* deg, int n) {
    int i = blockIdx.x * blockDim.x + threadIdx.x;
    if (i < n) deg[i] = 1.0f;
}

// deg[col[e]] += 1
__global__ void k_deg(const int* __restrict__ col, float* deg, int E) {
    int e = blockIdx.x * blockDim.x + threadIdx.x;
    if (e < E) atomAddF(&deg[col[e]], 1.0f);
}

// in-place deg -> rsqrt(deg)  (deg >= 1 always, self-loops)
__global__ void k_rsqrt(float* deg, int n) {
    int i = blockIdx.x * blockDim.x + threadIdx.x;
    if (i < n) deg[i] = rsqrtf(deg[i]);
}

// HS = dinv ⊙ (X @ W); ACC initialized to HS (self-loop contribution).
// Mapping: block=256 threads covers 64 rows. thread t: colchunk=(t&31)*4,
// rowgroup=(t>>5) -> 8 rows each. acc[8] float4 in regs. W read from global
// (64KB, L2-hot). HS may alias X: each row is fully consumed into registers
// by its (lockstep) half-wave before any store — safe.
__global__ __launch_bounds__(256) void k_gemm(const float* X,
                                              const float* __restrict__ W,
                                              const float* __restrict__ dinv,
                                              float* HS, float* ACC, int n) {
    const int t = threadIdx.x;
    const int cc = (t & 31) * 4;        // output col base
    const int rbase = blockIdx.x * 64 + (t >> 5) * 8;

    float4 acc[8];
#pragma unroll
    for (int r = 0; r < 8; ++r) acc[r] = make_float4(0.f, 0.f, 0.f, 0.f);

    for (int k4 = 0; k4 < HD / 4; ++k4) {
        float4 xq[8];
#pragma unroll
        for (int r = 0; r < 8; ++r) {
            const int row = rbase + r;
            xq[r] = (row < n) ? *(const float4*)&X[(size_t)row * HD + k4 * 4]
                              : make_float4(0.f, 0.f, 0.f, 0.f);
        }
#pragma unroll
        for (int kk = 0; kk < 4; ++kk) {
            const float4 w = *(const float4*)&W[(size_t)(k4 * 4 + kk) * HD + cc];
#pragma unroll
            for (int r = 0; r < 8; ++r) {
                const float xv = (kk == 0) ? xq[r].x : (kk == 1) ? xq[r].y
                               : (kk == 2) ? xq[r].z : xq[r].w;
                acc[r].x = fmaf(xv, w.x, acc[r].x);
                acc[r].y = fmaf(xv, w.y, acc[r].y);
                acc[r].z = fmaf(xv, w.z, acc[r].z);
                acc[r].w = fmaf(xv, w.w, acc[r].w);
            }
        }
    }
#pragma unroll
    for (int r = 0; r < 8; ++r) {
        const int row = rbase + r;
        if (row < n) {
            const float d = dinv[row];
            float4 v = acc[r];
            v.x *= d; v.y *= d; v.z *= d; v.w *= d;
            *(float4*)&HS[(size_t)row * HD + cc] = v;
            *(float4*)&ACC[(size_t)row * HD + cc] = v;
        }
    }
}

// For each edge e: ACC[col[e]] += HS[row[e]]   (128 f32, 32 threads/edge)
__global__ __launch_bounds__(256) void k_scatter(const int* __restrict__ rowi,
                                                 const int* __restrict__ coli,
                                                 const float* __restrict__ HS,
                                                 float* ACC, int E) {
    const int gid = blockIdx.x * blockDim.x + threadIdx.x;
    const int e = gid >> 5;
    if (e >= E) return;
    const int j = (gid & 31) * 4;
    const int src = rowi[e];
    const int dst = coli[e];
    const float4 v = *(const float4*)&HS[(size_t)src * HD + j];
    float* p = &ACC[(size_t)dst * HD + j];
    atomAddF(p + 0, v.x);
    atomAddF(p + 1, v.y);
    atomAddF(p + 2, v.z);
    atomAddF(p + 3, v.w);
}

// in-place: ACC = [relu]( dinv[i]*ACC + b[c] )
__global__ void k_epi(float* ACC, const float* __restrict__ dinv,
                      const float* __restrict__ b, int n, int relu) {
    const int gid = blockIdx.x * blockDim.x + threadIdx.x;
    const int i = gid >> 5;
    if (i >= n) return;
    const int j = (gid & 31) * 4;
    const float d = dinv[i];
    float4 v = *(float4*)&ACC[(size_t)i * HD + j];
    const float4 bv = *(const float4*)&b[j];
    v.x = fmaf(v.x, d, bv.x);
    v.y = fmaf(v.y, d, bv.y);
    v.z = fmaf(v.z, d, bv.z);
    v.w = fmaf(v.w, d, bv.w);
    if (relu) {
        v.x = fmaxf(v.x, 0.f); v.y = fmaxf(v.y, 0.f);
        v.z = fmaxf(v.z, 0.f); v.w = fmaxf(v.w, 0.f);
    }
    *(float4*)&ACC[(size_t)i * HD + j] = v;
}

__global__ void k_zero(float* p, int n) {
    int i = blockIdx.x * blockDim.x + threadIdx.x;
    if (i < n) p[i] = 0.f;
}

// gsum[batch[i]] += X[i]; gcnt[batch[i]] += 1
__global__ void k_pool(const float* __restrict__ X, const int* __restrict__ batch,
                       float* gsum, float* gcnt, int n) {
    const int gid = blockIdx.x * blockDim.x + threadIdx.x;
    const int i = gid >> 5;
    if (i >= n) return;
    const int j = (gid & 31) * 4;
    const int g = batch[i];
    const float4 v = *(const float4*)&X[(size_t)i * HD + j];
    float* p = &gsum[(size_t)g * HD + j];
    atomAddF(p + 0, v.x);
    atomAddF(p + 1, v.y);
    atomAddF(p + 2, v.z);
    atomAddF(p + 3, v.w);
    if ((gid & 31) == 0) atomAddF(&gcnt[g], 1.0f);
}

// out[g,c] = (gsum[g]/max(cnt,1)) . Wl[:,c] + bl[c]
__global__ void k_final(const float* __restrict__ gsum, const float* __restrict__ gcnt,
                        const float* __restrict__ Wl, const float* __restrict__ bl,
                        float* out, int total, int C) {
    const int gid = blockIdx.x * blockDim.x + threadIdx.x;
    if (gid >= total) return;
    const int g = gid / C;
    const int c = gid % C;
    float s = 0.f;
    for (int k = 0; k < HD; ++k)
        s = fmaf(gsum[(size_t)g * HD + k], Wl[(size_t)k * C + c], s);
    const float cnt = fmaxf(gcnt[g], 1.0f);
    out[gid] = s / cnt + bl[c];
}

extern "C" void kernel_launch(void* const* d_in, const int* in_sizes, int n_in,
                              void* d_out, int out_size, void* d_ws, size_t ws_size,
                              hipStream_t stream) {
    const float* x  = (const float*)d_in[0];
    const int* ei   = (const int*)d_in[1];
    const int* batch = (const int*)d_in[2];
    const float* W1 = (const float*)d_in[3];
    const float* b1 = (const float*)d_in[4];
    const float* W2 = (const float*)d_in[5];
    const float* b2 = (const float*)d_in[6];
    const float* W3 = (const float*)d_in[7];
    const float* b3 = (const float*)d_in[8];
    const float* Wl = (const float*)d_in[9];
    const float* bl = (const float*)d_in[10];
    float* out = (float*)d_out;

    const int N = in_sizes[0] / HD;
    const int E = in_sizes[1] / 2;
    const int C = 10;
    const int G = out_size / C;

    const int* rowi = ei;       // edge_index[0] = sources
    const int* coli = ei + E;   // edge_index[1] = targets

    // workspace layout (floats)
    float* B0   = (float*)d_ws;                 // N*HD
    float* B1   = B0 + (size_t)N * HD;          // N*HD
    float* dinv = B1 + (size_t)N * HD;          // N
    float* gsum = dinv + N;                     // G*HD
    float* gcnt = gsum + (size_t)G * HD;        // G   (contiguous after gsum)

    const int T = 256;
    // degree -> dinv
    k_fill1<<<(N + T - 1) / T, T, 0, stream>>>(dinv, N);
    k_deg<<<(E + T - 1) / T, T, 0, stream>>>(coli, dinv, E);
    k_rsqrt<<<(N + T - 1) / T, T, 0, stream>>>(dinv, N);

    const int gGemm = (N + 63) / 64;
    const int gScat = (E * 32 + T - 1) / T;
    const int gNode = (N * 32 + T - 1) / T;

    // Layer 1: IN=x, HS=B0, ACC=B1 -> X1 = B1
    k_gemm<<<gGemm, T, 0, stream>>>(x, W1, dinv, B0, B1, N);
    k_scatter<<<gScat, T, 0, stream>>>(rowi, coli, B0, B1, E);
    k_epi<<<gNode, T, 0, stream>>>(B1, dinv, b1, N, 1);

    // Layer 2: IN=B1, HS=B1 (alias-safe), ACC=B0 -> X2 = B0
    k_gemm<<<gGemm, T, 0, stream>>>(B1, W2, dinv, B1, B0, N);
    k_scatter<<<gScat, T, 0, stream>>>(rowi, coli, B1, B0, E);
    k_epi<<<gNode, T, 0, stream>>>(B0, dinv, b2, N, 1);

    // Layer 3: IN=B0, HS=B0, ACC=B1 -> X3 = B1 (no relu)
    k_gemm<<<gGemm, T, 0, stream>>>(B0, W3, dinv, B0, B1, N);
    k_scatter<<<gScat, T, 0, stream>>>(rowi, coli, B0, B1, E);
    k_epi<<<gNode, T, 0, stream>>>(B1, dinv, b3, N, 0);

    // Pooling
    k_zero<<<(G * HD + G + T - 1) / T, T, 0, stream>>>(gsum, G * HD + G);
    k_pool<<<gNode, T, 0, stream>>>(B1, batch, gsum, gcnt, N);

    // Final linear
    k_final<<<(G * C + T - 1) / T, T, 0, stream>>>(gsum, gcnt, Wl, bl, out, G * C, C);
}

// Round 3
// 865.496 us; speedup vs baseline: 5.7256x; 5.7256x over previous
//
#include <hip/hip_runtime.h>
#include <cstddef>

// N=100000, E=800000, H=128, C=10, G=512
#define HD 128
#define SCAN_BS 256
#define SCAN_CHUNK 2048  // 8 elements per thread

static __device__ __forceinline__ int atomAddI(int* p, int v) {
    return __hip_atomic_fetch_add(p, v, __ATOMIC_RELAXED, __HIP_MEMORY_SCOPE_AGENT);
}

__global__ void k_zero_int(int* p, int n) {
    int i = blockIdx.x * blockDim.x + threadIdx.x;
    if (i < n) p[i] = 0;
}

// cnt[col[e]] += 1   (int histogram of destinations)
__global__ void k_deg_int(const int* __restrict__ col, int* cnt, int E) {
    int e = blockIdx.x * blockDim.x + threadIdx.x;
    if (e < E) atomAddI(&cnt[col[e]], 1);
}

// Per-chunk exclusive scan of cnt -> rowptr (local), block totals -> bsum
__global__ __launch_bounds__(SCAN_BS) void k_scan1(const int* __restrict__ cnt,
                                                   int* __restrict__ rowptr,
                                                   int* __restrict__ bsum, int n) {
    __shared__ int sd[SCAN_BS];
    const int t = threadIdx.x;
    const int base = blockIdx.x * SCAN_CHUNK + t * 8;
    int loc[8];
    int tsum = 0;
#pragma unroll
    for (int i = 0; i < 8; ++i) {
        loc[i] = (base + i < n) ? cnt[base + i] : 0;
        tsum += loc[i];
    }
    sd[t] = tsum;
    __syncthreads();
    for (int off = 1; off < SCAN_BS; off <<= 1) {
        int u = (t >= off) ? sd[t - off] : 0;
        __syncthreads();
        sd[t] += u;
        __syncthreads();
    }
    const int texc = sd[t] - tsum;  // exclusive prefix of thread sums
    if (t == SCAN_BS - 1) bsum[blockIdx.x] = sd[t];
    int pos = texc;
#pragma unroll
    for (int i = 0; i < 8; ++i) {
        if (base + i < n) rowptr[base + i] = pos;
        pos += loc[i];
    }
}

// Serial exclusive scan of block sums (nblk ~ 49), set rowptr[n]=E
__global__ void k_scan2(int* bsum, int nblk, int* rowptr, int n) {
    if (threadIdx.x == 0 && blockIdx.x == 0) {
        int run = 0;
        for (int i = 0; i < nblk; ++i) { int v = bsum[i]; bsum[i] = run; run += v; }
        rowptr[n] = run;
    }
}

// Add block offsets; duplicate into wofs (write cursors for CSR fill)
__global__ void k_scan3(int* rowptr, int* wofs, const int* __restrict__ bsum, int n) {
    int i = blockIdx.x * blockDim.x + threadIdx.x;
    if (i < n) {
        int v = rowptr[i] + bsum[i >> 11];  // SCAN_CHUNK = 2048
        rowptr[i] = v;
        wofs[i] = v;
    }
}

// dinv[i] = rsqrt(1 + cnt[i])   (self-loop included)
__global__ void k_dinv(const int* __restrict__ cnt, float* dinv, int n) {
    int i = blockIdx.x * blockDim.x + threadIdx.x;
    if (i < n) dinv[i] = rsqrtf(1.0f + (float)cnt[i]);
}

// csr_src[pos++] = src, bucketed by dst
__global__ void k_fill_csr(const int* __restrict__ rowi, const int* __restrict__ coli,
                           int* wofs, int* __restrict__ csr_src, int E) {
    int e = blockIdx.x * blockDim.x + threadIdx.x;
    if (e >= E) return;
    int p = atomAddI(&wofs[coli[e]], 1);
    csr_src[p] = rowi[e];
}

// HS = dinv ⊙ (X @ W). block=256 covers 64 rows; thread: 8 rows x 4 cols.
// HS may alias X: each row is fully consumed into registers (all loads precede
// all stores in each lockstep half-wave that owns the row).
__global__ __launch_bounds__(256) void k_gemm(const float* X,
                                              const float* __restrict__ W,
                                              const float* __restrict__ dinv,
                                              float* HS, int n) {
    const int t = threadIdx.x;
    const int cc = (t & 31) * 4;
    const int rbase = blockIdx.x * 64 + (t >> 5) * 8;

    float4 acc[8];
#pragma unroll
    for (int r = 0; r < 8; ++r) acc[r] = make_float4(0.f, 0.f, 0.f, 0.f);

    for (int k4 = 0; k4 < HD / 4; ++k4) {
        float4 xq[8];
#pragma unroll
        for (int r = 0; r < 8; ++r) {
            const int row = rbase + r;
            xq[r] = (row < n) ? *(const float4*)&X[(size_t)row * HD + k4 * 4]
                              : make_float4(0.f, 0.f, 0.f, 0.f);
        }
#pragma unroll
        for (int kk = 0; kk < 4; ++kk) {
            const float4 w = *(const float4*)&W[(size_t)(k4 * 4 + kk) * HD + cc];
#pragma unroll
            for (int r = 0; r < 8; ++r) {
                const float xv = (kk == 0) ? xq[r].x : (kk == 1) ? xq[r].y
                               : (kk == 2) ? xq[r].z : xq[r].w;
                acc[r].x = fmaf(xv, w.x, acc[r].x);
                acc[r].y = fmaf(xv, w.y, acc[r].y);
                acc[r].z = fmaf(xv, w.z, acc[r].z);
                acc[r].w = fmaf(xv, w.w, acc[r].w);
            }
        }
    }
#pragma unroll
    for (int r = 0; r < 8; ++r) {
        const int row = rbase + r;
        if (row < n) {
            const float d = dinv[row];
            float4 v = acc[r];
            v.x *= d; v.y *= d; v.z *= d; v.w *= d;
            *(float4*)&HS[(size_t)row * HD + cc] = v;
        }
    }
}

// OUT[i] = [relu]( dinv[i]*(HS[i] + sum_{e in CSR[i]} HS[src_e]) + b )
// One wave (64 lanes) per node; node index forced to SGPR so the CSR index
// loads become scalar loads; HS row gathers are 512B coalesced per wave.
__global__ __launch_bounds__(256) void k_gather(const int* __restrict__ rowptr,
                                                const int* __restrict__ csr_src,
                                                const float* __restrict__ HS,
                                                const float* __restrict__ dinv,
                                                const float* __restrict__ b,
                                                float* __restrict__ OUT,
                                                int n, int relu) {
    const int node = __builtin_amdgcn_readfirstlane(blockIdx.x * 4 + (threadIdx.x >> 6));
    if (node >= n) return;
    const int lane = threadIdx.x & 63;
    const int j = lane * 2;
    float2 acc = *(const float2*)&HS[(size_t)node * HD + j];  // self loop
    const int s = rowptr[node];
    const int e = rowptr[node + 1];
    int k = s;
    for (; k + 1 < e; k += 2) {  // 2-way unroll: overlap dependent gathers
        const int s0 = csr_src[k];
        const int s1 = csr_src[k + 1];
        const float2 v0 = *(const float2*)&HS[(size_t)s0 * HD + j];
        const float2 v1 = *(const float2*)&HS[(size_t)s1 * HD + j];
        acc.x += v0.x + v1.x;
        acc.y += v0.y + v1.y;
    }
    if (k < e) {
        const int s0 = csr_src[k];
        const float2 v0 = *(const float2*)&HS[(size_t)s0 * HD + j];
        acc.x += v0.x;
        acc.y += v0.y;
    }
    const float d = dinv[node];
    const float2 bv = *(const float2*)&b[j];
    float ox = fmaf(acc.x, d, bv.x);
    float oy = fmaf(acc.y, d, bv.y);
    if (relu) { ox = fmaxf(ox, 0.f); oy = fmaxf(oy, 0.f); }
    *(float2*)&OUT[(size_t)node * HD + j] = make_float2(ox, oy);
}

// One block per graph; batch is sorted so boundaries via binary search.
// pooled[g] = mean over rows of X in [start,end)
__global__ __launch_bounds__(128) void k_pool_seg(const float* __restrict__ X,
                                                  const int* __restrict__ batch,
                                                  float* pooled, int n) {
    const int g = blockIdx.x;
    const int t = threadIdx.x;
    int lo = 0, hi = n;
    while (lo < hi) { int m = (lo + hi) >> 1; if (batch[m] < g) lo = m + 1; else hi = m; }
    const int start = lo;
    hi = n;
    while (lo < hi) { int m = (lo + hi) >> 1; if (batch[m] < g + 1) lo = m + 1; else hi = m; }
    const int end = lo;
    float acc = 0.f;
    for (int i = start; i < end; ++i) acc += X[(size_t)i * HD + t];
    pooled[(size_t)g * HD + t] = acc / (float)max(end - start, 1);
}

// out[g,c] = pooled[g] . Wl[:,c] + bl[c]
__global__ void k_final(const float* __restrict__ pooled, const float* __restrict__ Wl,
                        const float* __restrict__ bl, float* out, int total, int C) {
    const int gid = blockIdx.x * blockDim.x + threadIdx.x;
    if (gid >= total) return;
    const int g = gid / C;
    const int c = gid % C;
    float s = 0.f;
    for (int k = 0; k < HD; ++k)
        s = fmaf(pooled[(size_t)g * HD + k], Wl[(size_t)k * C + c], s);
    out[gid] = s + bl[c];
}

extern "C" void kernel_launch(void* const* d_in, const int* in_sizes, int n_in,
                              void* d_out, int out_size, void* d_ws, size_t ws_size,
                              hipStream_t stream) {
    const float* x   = (const float*)d_in[0];
    const int* ei    = (const int*)d_in[1];
    const int* batch = (const int*)d_in[2];
    const float* W1 = (const float*)d_in[3];
    const float* b1 = (const float*)d_in[4];
    const float* W2 = (const float*)d_in[5];
    const float* b2 = (const float*)d_in[6];
    const float* W3 = (const float*)d_in[7];
    const float* b3 = (const float*)d_in[8];
    const float* Wl = (const float*)d_in[9];
    const float* bl = (const float*)d_in[10];
    float* out = (float*)d_out;

    const int N = in_sizes[0] / HD;
    const int E = in_sizes[1] / 2;
    const int C = 10;
    const int G = out_size / C;

    const int* rowi = ei;      // sources
    const int* coli = ei + E;  // targets

    // workspace layout
    float* B0     = (float*)d_ws;                    // N*HD
    float* B1     = B0 + (size_t)N * HD;             // N*HD
    float* dinv   = B1 + (size_t)N * HD;             // N
    float* pooled = dinv + N;                        // G*HD
    int* rowptr   = (int*)(pooled + (size_t)G * HD); // N+1
    int* wofs     = rowptr + (N + 1);                // N
    int* cnt      = wofs + N;                        // N
    int* bsum     = cnt + N;                         // 64
    int* csr_src  = bsum + 64;                       // E

    const int T = 256;
    const int nblk = (N + SCAN_CHUNK - 1) / SCAN_CHUNK;

    // ---- CSR + dinv preprocessing (once per call) ----
    k_zero_int<<<(N + T - 1) / T, T, 0, stream>>>(cnt, N);
    k_deg_int<<<(E + T - 1) / T, T, 0, stream>>>(coli, cnt, E);
    k_scan1<<<nblk, SCAN_BS, 0, stream>>>(cnt, rowptr, bsum, N);
    k_scan2<<<1, 64, 0, stream>>>(bsum, nblk, rowptr, N);
    k_scan3<<<(N + T - 1) / T, T, 0, stream>>>(rowptr, wofs, bsum, N);
    k_dinv<<<(N + T - 1) / T, T, 0, stream>>>(cnt, dinv, N);
    k_fill_csr<<<(E + T - 1) / T, T, 0, stream>>>(rowi, coli, wofs, csr_src, E);

    const int gGemm   = (N + 63) / 64;
    const int gGather = (N + 3) / 4;

    // Layer 1: x -> HS=B0 -> X1=B1
    k_gemm<<<gGemm, T, 0, stream>>>(x, W1, dinv, B0, N);
    k_gather<<<gGather, T, 0, stream>>>(rowptr, csr_src, B0, dinv, b1, B1, N, 1);

    // Layer 2: B1 -> HS=B1 (alias-safe) -> X2=B0
    k_gemm<<<gGemm, T, 0, stream>>>(B1, W2, dinv, B1, N);
    k_gather<<<gGather, T, 0, stream>>>(rowptr, csr_src, B1, dinv, b2, B0, N, 1);

    // Layer 3: B0 -> HS=B0 (alias-safe) -> X3=B1 (no relu)
    k_gemm<<<gGemm, T, 0, stream>>>(B0, W3, dinv, B0, N);
    k_gather<<<gGather, T, 0, stream>>>(rowptr, csr_src, B0, dinv, b3, B1, N, 0);

    // Pool (segmented, no atomics) + final linear
    k_pool_seg<<<G, 128, 0, stream>>>(B1, batch, pooled, N);
    k_final<<<(G * C + T - 1) / T, T, 0, stream>>>(pooled, Wl, bl, out, G * C, C);
}

// Round 4
// 481.295 us; speedup vs baseline: 10.2961x; 1.7983x over previous
//
#include <hip/hip_runtime.h>
#include <cstddef>

// N=100000, E=800000, H=128, C=10, G=512
#define HD 128
#define SCAN_BS 256
#define SCAN_CHUNK 2048  // 8 elements per thread

typedef float f32x4 __attribute__((ext_vector_type(4)));
typedef short s16x8 __attribute__((ext_vector_type(8)));

static __device__ __forceinline__ int atomAddI(int* p, int v) {
    return __hip_atomic_fetch_add(p, v, __ATOMIC_RELAXED, __HIP_MEMORY_SCOPE_AGENT);
}

// round-to-nearest-even f32 -> bf16 bits
static __device__ __forceinline__ unsigned short rne_bf16(float f) {
    unsigned u = __float_as_uint(f);
    unsigned r = u + 0x7FFFu + ((u >> 16) & 1u);
    return (unsigned short)(r >> 16);
}
static __device__ __forceinline__ float bf16_to_f32(unsigned short h) {
    return __uint_as_float((unsigned)h << 16);
}

__global__ void k_zero_int(int* p, int n) {
    int i = blockIdx.x * blockDim.x + threadIdx.x;
    if (i < n) p[i] = 0;
}

__global__ void k_deg_int(const int* __restrict__ col, int* cnt, int E) {
    int e = blockIdx.x * blockDim.x + threadIdx.x;
    if (e < E) atomAddI(&cnt[col[e]], 1);
}

__global__ __launch_bounds__(SCAN_BS) void k_scan1(const int* __restrict__ cnt,
                                                   int* __restrict__ rowptr,
                                                   int* __restrict__ bsum, int n) {
    __shared__ int sd[SCAN_BS];
    const int t = threadIdx.x;
    const int base = blockIdx.x * SCAN_CHUNK + t * 8;
    int loc[8];
    int tsum = 0;
#pragma unroll
    for (int i = 0; i < 8; ++i) {
        loc[i] = (base + i < n) ? cnt[base + i] : 0;
        tsum += loc[i];
    }
    sd[t] = tsum;
    __syncthreads();
    for (int off = 1; off < SCAN_BS; off <<= 1) {
        int u = (t >= off) ? sd[t - off] : 0;
        __syncthreads();
        sd[t] += u;
        __syncthreads();
    }
    const int texc = sd[t] - tsum;
    if (t == SCAN_BS - 1) bsum[blockIdx.x] = sd[t];
    int pos = texc;
#pragma unroll
    for (int i = 0; i < 8; ++i) {
        if (base + i < n) rowptr[base + i] = pos;
        pos += loc[i];
    }
}

__global__ void k_scan2(int* bsum, int nblk, int* rowptr, int n) {
    if (threadIdx.x == 0 && blockIdx.x == 0) {
        int run = 0;
        for (int i = 0; i < nblk; ++i) { int v = bsum[i]; bsum[i] = run; run += v; }
        rowptr[n] = run;
    }
}

__global__ void k_scan3(int* rowptr, int* wofs, const int* __restrict__ bsum, int n) {
    int i = blockIdx.x * blockDim.x + threadIdx.x;
    if (i < n) {
        int v = rowptr[i] + bsum[i >> 11];  // SCAN_CHUNK = 2048
        rowptr[i] = v;
        wofs[i] = v;
    }
}

__global__ void k_dinv(const int* __restrict__ cnt, float* dinv, int n) {
    int i = blockIdx.x * blockDim.x + threadIdx.x;
    if (i < n) dinv[i] = rsqrtf(1.0f + (float)cnt[i]);
}

__global__ void k_fill_csr(const int* __restrict__ rowi, const int* __restrict__ coli,
                           int* wofs, int* __restrict__ csr_src, int E) {
    int e = blockIdx.x * blockDim.x + threadIdx.x;
    if (e >= E) return;
    int p = atomAddI(&wofs[coli[e]], 1);
    csr_src[p] = rowi[e];
}

// Precompute W (128x128 f32) into MFMA B-fragment order, split hi/lo bf16.
// B-frag for 16x16x32: lane l holds B[k = kt*32+(l>>4)*8+e][col = nt*16+(l&15)].
// Layout: wf[w][hi/lo][((nt*4+kt)*64+lane)*8 + e], 16384 shorts per half.
__global__ __launch_bounds__(256) void k_wfrag(const float* __restrict__ W1,
                                               const float* __restrict__ W2,
                                               const float* __restrict__ W3,
                                               short* __restrict__ wf) {
    const int w = blockIdx.x >> 3;
    const int slot = (blockIdx.x & 7) * 256 + threadIdx.x;  // 0..2047
    const int nt = slot >> 8;
    const int kt = (slot >> 6) & 3;
    const int lane = slot & 63;
    const float* W = (w == 0) ? W1 : (w == 1) ? W2 : W3;
    short* whi = wf + (size_t)w * 32768;
    short* wlo = whi + 16384;
    const int obase = ((nt * 4 + kt) * 64 + lane) * 8;
    s16x8 hi8, lo8;
#pragma unroll
    for (int e = 0; e < 8; ++e) {
        const int k = kt * 32 + (lane >> 4) * 8 + e;
        const int c = nt * 16 + (lane & 15);
        const float v = W[(size_t)k * HD + c];
        const unsigned short h = rne_bf16(v);
        hi8[e] = (short)h;
        lo8[e] = (short)rne_bf16(v - bf16_to_f32(h));
    }
    *(s16x8*)&whi[obase] = hi8;
    *(s16x8*)&wlo[obase] = lo8;
}

// HS = dinv ⊙ (X @ W) via split-bf16 MFMA (3 products: hh + lh + hl).
// Block = 4 waves; wave computes 16 rows x 128 cols. A converted on the fly.
// In-place safe (HS may alias X): each wave's A loads (its own 16 rows only)
// complete (data dep through acc) before its stores; other waves touch
// disjoint rows; OOB-clamped rows never have their garbage stored.
__global__ __launch_bounds__(256) void k_gemm(const float* __restrict__ X,
                                              const short* __restrict__ whi,
                                              const short* __restrict__ wlo,
                                              const float* __restrict__ dinv,
                                              float* __restrict__ HS, int n) {
    const int lane = threadIdx.x & 63;
    const int wid = threadIdx.x >> 6;
    const int rbase = blockIdx.x * 64 + wid * 16;
    const int arow = min(rbase + (lane & 15), n - 1);
    const int kbase = (lane >> 4) * 8;

    f32x4 acc[8];
#pragma unroll
    for (int nt = 0; nt < 8; ++nt) acc[nt] = (f32x4){0.f, 0.f, 0.f, 0.f};

#pragma unroll
    for (int kt = 0; kt < 4; ++kt) {
        // load + split this wave's A fragment (8 f32 per lane)
        const float4 x0 = *(const float4*)&X[(size_t)arow * HD + kt * 32 + kbase];
        const float4 x1 = *(const float4*)&X[(size_t)arow * HD + kt * 32 + kbase + 4];
        float xs[8] = {x0.x, x0.y, x0.z, x0.w, x1.x, x1.y, x1.z, x1.w};
        s16x8 ahi, alo;
#pragma unroll
        for (int e = 0; e < 8; ++e) {
            const unsigned short h = rne_bf16(xs[e]);
            ahi[e] = (short)h;
            alo[e] = (short)rne_bf16(xs[e] - bf16_to_f32(h));
        }
#pragma unroll
        for (int nt = 0; nt < 8; ++nt) {
            const int fo = ((nt * 4 + kt) * 64 + lane) * 8;
            const s16x8 bhi = *(const s16x8*)&whi[fo];
            const s16x8 blo = *(const s16x8*)&wlo[fo];
            acc[nt] = __builtin_amdgcn_mfma_f32_16x16x32_bf16(ahi, bhi, acc[nt], 0, 0, 0);
            acc[nt] = __builtin_amdgcn_mfma_f32_16x16x32_bf16(alo, bhi, acc[nt], 0, 0, 0);
            acc[nt] = __builtin_amdgcn_mfma_f32_16x16x32_bf16(ahi, blo, acc[nt], 0, 0, 0);
        }
    }

    // C/D layout: col = lane&15, row = (lane>>4)*4 + reg
    const int rowg = rbase + (lane >> 4) * 4;
    const int colb = lane & 15;
#pragma unroll
    for (int r = 0; r < 4; ++r) {
        const int row = rowg + r;
        if (row < n) {
            const float d = dinv[row];
#pragma unroll
            for (int nt = 0; nt < 8; ++nt)
                HS[(size_t)row * HD + nt * 16 + colb] = acc[nt][r] * d;
        }
    }
}

// OUT[i] = [relu]( dinv[i]*(HS[i] + sum_{e in CSR[i]} HS[src_e]) + b )
// One wave per node (node idx in SGPR -> scalar CSR loads); 4-wide unroll.
__global__ __launch_bounds__(256) void k_gather(const int* __restrict__ rowptr,
                                                const int* __restrict__ csr_src,
                                                const float* __restrict__ HS,
                                                const float* __restrict__ dinv,
                                                const float* __restrict__ b,
                                                float* __restrict__ OUT,
                                                int n, int relu) {
    const int node = __builtin_amdgcn_readfirstlane(blockIdx.x * 4 + (threadIdx.x >> 6));
    if (node >= n) return;
    const int lane = threadIdx.x & 63;
    const int j = lane * 2;
    float2 acc = *(const float2*)&HS[(size_t)node * HD + j];  // self loop
    const int s = rowptr[node];
    const int e = rowptr[node + 1];
    int k = s;
    for (; k + 3 < e; k += 4) {
        const int s0 = csr_src[k], s1 = csr_src[k + 1];
        const int s2 = csr_src[k + 2], s3 = csr_src[k + 3];
        const float2 v0 = *(const float2*)&HS[(size_t)s0 * HD + j];
        const float2 v1 = *(const float2*)&HS[(size_t)s1 * HD + j];
        const float2 v2 = *(const float2*)&HS[(size_t)s2 * HD + j];
        const float2 v3 = *(const float2*)&HS[(size_t)s3 * HD + j];
        acc.x += (v0.x + v1.x) + (v2.x + v3.x);
        acc.y += (v0.y + v1.y) + (v2.y + v3.y);
    }
    for (; k < e; ++k) {
        const int s0 = csr_src[k];
        const float2 v0 = *(const float2*)&HS[(size_t)s0 * HD + j];
        acc.x += v0.x;
        acc.y += v0.y;
    }
    const float d = dinv[node];
    const float2 bv = *(const float2*)&b[j];
    float ox = fmaf(acc.x, d, bv.x);
    float oy = fmaf(acc.y, d, bv.y);
    if (relu) { ox = fmaxf(ox, 0.f); oy = fmaxf(oy, 0.f); }
    *(float2*)&OUT[(size_t)node * HD + j] = make_float2(ox, oy);
}

__global__ __launch_bounds__(128) void k_pool_seg(const float* __restrict__ X,
                                                  const int* __restrict__ batch,
                                                  float* pooled, int n) {
    const int g = blockIdx.x;
    const int t = threadIdx.x;
    int lo = 0, hi = n;
    while (lo < hi) { int m = (lo + hi) >> 1; if (batch[m] < g) lo = m + 1; else hi = m; }
    const int start = lo;
    hi = n;
    while (lo < hi) { int m = (lo + hi) >> 1; if (batch[m] < g + 1) lo = m + 1; else hi = m; }
    const int end = lo;
    float acc = 0.f;
    for (int i = start; i < end; ++i) acc += X[(size_t)i * HD + t];
    pooled[(size_t)g * HD + t] = acc / (float)max(end - start, 1);
}

__global__ void k_final(const float* __restrict__ pooled, const float* __restrict__ Wl,
                        const float* __restrict__ bl, float* out, int total, int C) {
    const int gid = blockIdx.x * blockDim.x + threadIdx.x;
    if (gid >= total) return;
    const int g = gid / C;
    const int c = gid % C;
    float s = 0.f;
    for (int k = 0; k < HD; ++k)
        s = fmaf(pooled[(size_t)g * HD + k], Wl[(size_t)k * C + c], s);
    out[gid] = s + bl[c];
}

extern "C" void kernel_launch(void* const* d_in, const int* in_sizes, int n_in,
                              void* d_out, int out_size, void* d_ws, size_t ws_size,
                              hipStream_t stream) {
    const float* x   = (const float*)d_in[0];
    const int* ei    = (const int*)d_in[1];
    const int* batch = (const int*)d_in[2];
    const float* W1 = (const float*)d_in[3];
    const float* b1 = (const float*)d_in[4];
    const float* W2 = (const float*)d_in[5];
    const float* b2 = (const float*)d_in[6];
    const float* W3 = (const float*)d_in[7];
    const float* b3 = (const float*)d_in[8];
    const float* Wl = (const float*)d_in[9];
    const float* bl = (const float*)d_in[10];
    float* out = (float*)d_out;

    const int N = in_sizes[0] / HD;
    const int E = in_sizes[1] / 2;
    const int C = 10;
    const int G = out_size / C;

    const int* rowi = ei;      // sources
    const int* coli = ei + E;  // targets

    // workspace layout
    float* B0     = (float*)d_ws;                    // N*HD
    float* B1     = B0 + (size_t)N * HD;             // N*HD
    float* dinv   = B1 + (size_t)N * HD;             // N
    float* pooled = dinv + N;                        // G*HD
    short* wf     = (short*)(pooled + (size_t)G * HD); // 3*2*16384 shorts (16B-aligned)
    int* rowptr   = (int*)(wf + 3 * 32768);          // N+1
    int* wofs     = rowptr + (N + 1);                // N
    int* cnt      = wofs + N;                        // N
    int* bsum     = cnt + N;                         // 64
    int* csr_src  = bsum + 64;                       // E

    const int T = 256;
    const int nblk = (N + SCAN_CHUNK - 1) / SCAN_CHUNK;

    // ---- preprocessing: CSR, dinv, W fragments ----
    k_zero_int<<<(N + T - 1) / T, T, 0, stream>>>(cnt, N);
    k_deg_int<<<(E + T - 1) / T, T, 0, stream>>>(coli, cnt, E);
    k_scan1<<<nblk, SCAN_BS, 0, stream>>>(cnt, rowptr, bsum, N);
    k_scan2<<<1, 64, 0, stream>>>(bsum, nblk, rowptr, N);
    k_scan3<<<(N + T - 1) / T, T, 0, stream>>>(rowptr, wofs, bsum, N);
    k_dinv<<<(N + T - 1) / T, T, 0, stream>>>(cnt, dinv, N);
    k_fill_csr<<<(E + T - 1) / T, T, 0, stream>>>(rowi, coli, wofs, csr_src, E);
    k_wfrag<<<24, 256, 0, stream>>>(W1, W2, W3, wf);

    const short* whi1 = wf;                const short* wlo1 = wf + 16384;
    const short* whi2 = wf + 32768;        const short* wlo2 = wf + 49152;
    const short* whi3 = wf + 65536;        const short* wlo3 = wf + 81920;

    const int gGemm   = (N + 63) / 64;
    const int gGather = (N + 3) / 4;

    // Layer 1: x -> HS=B0 -> X1=B1
    k_gemm<<<gGemm, T, 0, stream>>>(x, whi1, wlo1, dinv, B0, N);
    k_gather<<<gGather, T, 0, stream>>>(rowptr, csr_src, B0, dinv, b1, B1, N, 1);

    // Layer 2: B1 -> HS=B1 (alias-safe) -> X2=B0
    k_gemm<<<gGemm, T, 0, stream>>>(B1, whi2, wlo2, dinv, B1, N);
    k_gather<<<gGather, T, 0, stream>>>(rowptr, csr_src, B1, dinv, b2, B0, N, 1);

    // Layer 3: B0 -> HS=B0 (alias-safe) -> X3=B1 (no relu)
    k_gemm<<<gGemm, T, 0, stream>>>(B0, whi3, wlo3, dinv, B0, N);
    k_gather<<<gGather, T, 0, stream>>>(rowptr, csr_src, B0, dinv, b3, B1, N, 0);

    // Pool + final linear
    k_pool_seg<<<G, 128, 0, stream>>>(B1, batch, pooled, N);
    k_final<<<(G * C + T - 1) / T, T, 0, stream>>>(pooled, Wl, bl, out, G * C, C);
}

// Round 5
// 431.073 us; speedup vs baseline: 11.4957x; 1.1165x over previous
//
#include <hip/hip_runtime.h>
#include <cstddef>

// N=100000, E=800000, H=128, C=10, G=512
#define HD 128
#define SCAN_BS 256
#define SCAN_CHUNK 2048  // 8 elements per thread
#define QSEG 8           // partial-pool blocks per graph

typedef float f32x4 __attribute__((ext_vector_type(4)));
typedef short s16x8 __attribute__((ext_vector_type(8)));

static __device__ __forceinline__ int atomAddI(int* p, int v) {
    return __hip_atomic_fetch_add(p, v, __ATOMIC_RELAXED, __HIP_MEMORY_SCOPE_AGENT);
}

// round-to-nearest-even f32 -> bf16 bits
static __device__ __forceinline__ unsigned short rne_bf16(float f) {
    unsigned u = __float_as_uint(f);
    unsigned r = u + 0x7FFFu + ((u >> 16) & 1u);
    return (unsigned short)(r >> 16);
}
static __device__ __forceinline__ float bf16_to_f32(unsigned short h) {
    return __uint_as_float((unsigned)h << 16);
}

__global__ void k_zero_int(int* p, int n) {
    int i = blockIdx.x * blockDim.x + threadIdx.x;
    if (i < n) p[i] = 0;
}

__global__ void k_deg_int(const int* __restrict__ col, int* cnt, int E) {
    int e = blockIdx.x * blockDim.x + threadIdx.x;
    if (e < E) atomAddI(&cnt[col[e]], 1);
}

__global__ __launch_bounds__(SCAN_BS) void k_scan1(const int* __restrict__ cnt,
                                                   int* __restrict__ rowptr,
                                                   int* __restrict__ bsum, int n) {
    __shared__ int sd[SCAN_BS];
    const int t = threadIdx.x;
    const int base = blockIdx.x * SCAN_CHUNK + t * 8;
    int loc[8];
    int tsum = 0;
#pragma unroll
    for (int i = 0; i < 8; ++i) {
        loc[i] = (base + i < n) ? cnt[base + i] : 0;
        tsum += loc[i];
    }
    sd[t] = tsum;
    __syncthreads();
    for (int off = 1; off < SCAN_BS; off <<= 1) {
        int u = (t >= off) ? sd[t - off] : 0;
        __syncthreads();
        sd[t] += u;
        __syncthreads();
    }
    const int texc = sd[t] - tsum;
    if (t == SCAN_BS - 1) bsum[blockIdx.x] = sd[t];
    int pos = texc;
#pragma unroll
    for (int i = 0; i < 8; ++i) {
        if (base + i < n) rowptr[base + i] = pos;
        pos += loc[i];
    }
}

__global__ void k_scan2(int* bsum, int nblk, int* rowptr, int n) {
    if (threadIdx.x == 0 && blockIdx.x == 0) {
        int run = 0;
        for (int i = 0; i < nblk; ++i) { int v = bsum[i]; bsum[i] = run; run += v; }
        rowptr[n] = run;
    }
}

// rowptr += block offset; wofs = rowptr; dinv = rsqrt(1+cnt)
__global__ void k_scan3(int* rowptr, int* wofs, const int* __restrict__ bsum,
                        const int* __restrict__ cnt, float* __restrict__ dinv, int n) {
    int i = blockIdx.x * blockDim.x + threadIdx.x;
    if (i < n) {
        int v = rowptr[i] + bsum[i >> 11];  // SCAN_CHUNK = 2048
        rowptr[i] = v;
        wofs[i] = v;
        dinv[i] = rsqrtf(1.0f + (float)cnt[i]);
    }
}

__global__ void k_fill_csr(const int* __restrict__ rowi, const int* __restrict__ coli,
                           int* wofs, int* __restrict__ csr_src, int E) {
    int e = blockIdx.x * blockDim.x + threadIdx.x;
    if (e >= E) return;
    int p = atomAddI(&wofs[coli[e]], 1);
    csr_src[p] = rowi[e];
}

// Precompute W (128x128 f32) into MFMA B-fragment order, split hi/lo bf16.
// B-frag for 16x16x32: lane l holds B[k = kt*32+(l>>4)*8+e][col = nt*16+(l&15)].
__global__ __launch_bounds__(256) void k_wfrag(const float* __restrict__ W1,
                                               const float* __restrict__ W2,
                                               const float* __restrict__ W3,
                                               short* __restrict__ wf) {
    const int w = blockIdx.x >> 3;
    const int slot = (blockIdx.x & 7) * 256 + threadIdx.x;  // 0..2047
    const int nt = slot >> 8;
    const int kt = (slot >> 6) & 3;
    const int lane = slot & 63;
    const float* W = (w == 0) ? W1 : (w == 1) ? W2 : W3;
    short* whi = wf + (size_t)w * 32768;
    short* wlo = whi + 16384;
    const int obase = ((nt * 4 + kt) * 64 + lane) * 8;
    s16x8 hi8, lo8;
#pragma unroll
    for (int e = 0; e < 8; ++e) {
        const int k = kt * 32 + (lane >> 4) * 8 + e;
        const int c = nt * 16 + (lane & 15);
        const float v = W[(size_t)k * HD + c];
        const unsigned short h = rne_bf16(v);
        hi8[e] = (short)h;
        lo8[e] = (short)rne_bf16(v - bf16_to_f32(h));
    }
    *(s16x8*)&whi[obase] = hi8;
    *(s16x8*)&wlo[obase] = lo8;
}

// HS = dinv ⊙ (X @ W) via split-bf16 MFMA (hh + lh + hl).
// Block = 4 waves; wave computes 16 rows x 128 cols. In-place safe.
__global__ __launch_bounds__(256) void k_gemm(const float* __restrict__ X,
                                              const short* __restrict__ whi,
                                              const short* __restrict__ wlo,
                                              const float* __restrict__ dinv,
                                              float* __restrict__ HS, int n) {
    const int lane = threadIdx.x & 63;
    const int wid = threadIdx.x >> 6;
    const int rbase = blockIdx.x * 64 + wid * 16;
    const int arow = min(rbase + (lane & 15), n - 1);
    const int kbase = (lane >> 4) * 8;

    f32x4 acc[8];
#pragma unroll
    for (int nt = 0; nt < 8; ++nt) acc[nt] = (f32x4){0.f, 0.f, 0.f, 0.f};

#pragma unroll
    for (int kt = 0; kt < 4; ++kt) {
        const float4 x0 = *(const float4*)&X[(size_t)arow * HD + kt * 32 + kbase];
        const float4 x1 = *(const float4*)&X[(size_t)arow * HD + kt * 32 + kbase + 4];
        float xs[8] = {x0.x, x0.y, x0.z, x0.w, x1.x, x1.y, x1.z, x1.w};
        s16x8 ahi, alo;
#pragma unroll
        for (int e = 0; e < 8; ++e) {
            const unsigned short h = rne_bf16(xs[e]);
            ahi[e] = (short)h;
            alo[e] = (short)rne_bf16(xs[e] - bf16_to_f32(h));
        }
#pragma unroll
        for (int nt = 0; nt < 8; ++nt) {
            const int fo = ((nt * 4 + kt) * 64 + lane) * 8;
            const s16x8 bhi = *(const s16x8*)&whi[fo];
            const s16x8 blo = *(const s16x8*)&wlo[fo];
            acc[nt] = __builtin_amdgcn_mfma_f32_16x16x32_bf16(ahi, bhi, acc[nt], 0, 0, 0);
            acc[nt] = __builtin_amdgcn_mfma_f32_16x16x32_bf16(alo, bhi, acc[nt], 0, 0, 0);
            acc[nt] = __builtin_amdgcn_mfma_f32_16x16x32_bf16(ahi, blo, acc[nt], 0, 0, 0);
        }
    }

    // C/D layout: col = lane&15, row = (lane>>4)*4 + reg
    const int rowg = rbase + (lane >> 4) * 4;
    const int colb = lane & 15;
#pragma unroll
    for (int r = 0; r < 4; ++r) {
        const int row = rowg + r;
        if (row < n) {
            const float d = dinv[row];
#pragma unroll
            for (int nt = 0; nt < 8; ++nt)
                HS[(size_t)row * HD + nt * 16 + colb] = acc[nt][r] * d;
        }
    }
}

// OUT[i] = [relu]( dinv[i]*(HS[i] + sum_{e in CSR[i]} HS[src_e]) + b )
__global__ __launch_bounds__(256) void k_gather(const int* __restrict__ rowptr,
                                                const int* __restrict__ csr_src,
                                                const float* __restrict__ HS,
                                                const float* __restrict__ dinv,
                                                const float* __restrict__ b,
                                                float* __restrict__ OUT,
                                                int n, int relu) {
    const int node = __builtin_amdgcn_readfirstlane(blockIdx.x * 4 + (threadIdx.x >> 6));
    if (node >= n) return;
    const int lane = threadIdx.x & 63;
    const int j = lane * 2;
    float2 acc = *(const float2*)&HS[(size_t)node * HD + j];  // self loop
    const int s = rowptr[node];
    const int e = rowptr[node + 1];
    int k = s;
    for (; k + 3 < e; k += 4) {
        const int s0 = csr_src[k], s1 = csr_src[k + 1];
        const int s2 = csr_src[k + 2], s3 = csr_src[k + 3];
        const float2 v0 = *(const float2*)&HS[(size_t)s0 * HD + j];
        const float2 v1 = *(const float2*)&HS[(size_t)s1 * HD + j];
        const float2 v2 = *(const float2*)&HS[(size_t)s2 * HD + j];
        const float2 v3 = *(const float2*)&HS[(size_t)s3 * HD + j];
        acc.x += (v0.x + v1.x) + (v2.x + v3.x);
        acc.y += (v0.y + v1.y) + (v2.y + v3.y);
    }
    for (; k < e; ++k) {
        const int s0 = csr_src[k];
        const float2 v0 = *(const float2*)&HS[(size_t)s0 * HD + j];
        acc.x += v0.x;
        acc.y += v0.y;
    }
    const float d = dinv[node];
    const float2 bv = *(const float2*)&b[j];
    float ox = fmaf(acc.x, d, bv.x);
    float oy = fmaf(acc.y, d, bv.y);
    if (relu) { ox = fmaxf(ox, 0.f); oy = fmaxf(oy, 0.f); }
    *(float2*)&OUT[(size_t)node * HD + j] = make_float2(ox, oy);
}

// Stage 1 pooling: QSEG blocks per graph; block (g,q) sums rows start+q,
// start+q+QSEG, ... over its graph segment -> psum[(g*QSEG+q)*HD + t].
// No init needed: every psum slot is written exactly once.
__global__ __launch_bounds__(128) void k_pool_part(const float* __restrict__ X,
                                                   const int* __restrict__ batch,
                                                   float* __restrict__ psum, int n) {
    const int g = blockIdx.x / QSEG;
    const int q = blockIdx.x % QSEG;
    const int t = threadIdx.x;
    int lo = 0, hi = n;
    while (lo < hi) { int m = (lo + hi) >> 1; if (batch[m] < g) lo = m + 1; else hi = m; }
    const int start = lo;
    hi = n;
    while (lo < hi) { int m = (lo + hi) >> 1; if (batch[m] < g + 1) lo = m + 1; else hi = m; }
    const int end = lo;
    float acc = 0.f;
    for (int i = start + q; i < end; i += QSEG) acc += X[(size_t)i * HD + t];
    psum[(size_t)blockIdx.x * HD + t] = acc;
}

// Stage 2 + final linear fused: block g: pooled = (sum_q psum)/cnt (in LDS),
// then threads c<C compute out[g,c] = pooled . Wl[:,c] + bl[c].
__global__ __launch_bounds__(128) void k_pool_final(const float* __restrict__ psum,
                                                    const int* __restrict__ batch,
                                                    const float* __restrict__ Wl,
                                                    const float* __restrict__ bl,
                                                    float* __restrict__ out, int n, int C) {
    __shared__ float pl[HD];
    const int g = blockIdx.x;
    const int t = threadIdx.x;
    int lo = 0, hi = n;
    while (lo < hi) { int m = (lo + hi) >> 1; if (batch[m] < g) lo = m + 1; else hi = m; }
    const int start = lo;
    hi = n;
    while (lo < hi) { int m = (lo + hi) >> 1; if (batch[m] < g + 1) lo = m + 1; else hi = m; }
    const int cnt = lo - start;
    float acc = 0.f;
#pragma unroll
    for (int q = 0; q < QSEG; ++q)
        acc += psum[((size_t)g * QSEG + q) * HD + t];
    pl[t] = acc / (float)max(cnt, 1);
    __syncthreads();
    if (t < C) {
        float s = 0.f;
        for (int k = 0; k < HD; ++k)
            s = fmaf(pl[k], Wl[(size_t)k * C + t], s);
        out[(size_t)g * C + t] = s + bl[t];
    }
}

extern "C" void kernel_launch(void* const* d_in, const int* in_sizes, int n_in,
                              void* d_out, int out_size, void* d_ws, size_t ws_size,
                              hipStream_t stream) {
    const float* x   = (const float*)d_in[0];
    const int* ei    = (const int*)d_in[1];
    const int* batch = (const int*)d_in[2];
    const float* W1 = (const float*)d_in[3];
    const float* b1 = (const float*)d_in[4];
    const float* W2 = (const float*)d_in[5];
    const float* b2 = (const float*)d_in[6];
    const float* W3 = (const float*)d_in[7];
    const float* b3 = (const float*)d_in[8];
    const float* Wl = (const float*)d_in[9];
    const float* bl = (const float*)d_in[10];
    float* out = (float*)d_out;

    const int N = in_sizes[0] / HD;
    const int E = in_sizes[1] / 2;
    const int C = 10;
    const int G = out_size / C;

    const int* rowi = ei;      // sources
    const int* coli = ei + E;  // targets

    // workspace layout
    float* B0     = (float*)d_ws;                    // N*HD
    float* B1     = B0 + (size_t)N * HD;             // N*HD
    float* dinv   = B1 + (size_t)N * HD;             // N
    short* wf     = (short*)(dinv + N);              // 3*2*16384 shorts
    int* rowptr   = (int*)(wf + 3 * 32768);          // N+1
    int* wofs     = rowptr + (N + 1);                // N
    int* cnt      = wofs + N;                        // N
    int* bsum     = cnt + N;                         // 64
    int* csr_src  = bsum + 64;                       // E
    float* psum   = B0;  // G*QSEG*HD floats (2MB) — B0 is dead after layer 3

    const int T = 256;
    const int nblk = (N + SCAN_CHUNK - 1) / SCAN_CHUNK;

    // ---- preprocessing: CSR, dinv, W fragments ----
    k_zero_int<<<(N + T - 1) / T, T, 0, stream>>>(cnt, N);
    k_deg_int<<<(E + T - 1) / T, T, 0, stream>>>(coli, cnt, E);
    k_scan1<<<nblk, SCAN_BS, 0, stream>>>(cnt, rowptr, bsum, N);
    k_scan2<<<1, 64, 0, stream>>>(bsum, nblk, rowptr, N);
    k_scan3<<<(N + T - 1) / T, T, 0, stream>>>(rowptr, wofs, bsum, cnt, dinv, N);
    k_fill_csr<<<(E + T - 1) / T, T, 0, stream>>>(rowi, coli, wofs, csr_src, E);
    k_wfrag<<<24, 256, 0, stream>>>(W1, W2, W3, wf);

    const short* whi1 = wf;                const short* wlo1 = wf + 16384;
    const short* whi2 = wf + 32768;        const short* wlo2 = wf + 49152;
    const short* whi3 = wf + 65536;        const short* wlo3 = wf + 81920;

    const int gGemm   = (N + 63) / 64;
    const int gGather = (N + 3) / 4;

    // Layer 1: x -> HS=B0 -> X1=B1
    k_gemm<<<gGemm, T, 0, stream>>>(x, whi1, wlo1, dinv, B0, N);
    k_gather<<<gGather, T, 0, stream>>>(rowptr, csr_src, B0, dinv, b1, B1, N, 1);

    // Layer 2: B1 -> HS=B1 (alias-safe) -> X2=B0
    k_gemm<<<gGemm, T, 0, stream>>>(B1, whi2, wlo2, dinv, B1, N);
    k_gather<<<gGather, T, 0, stream>>>(rowptr, csr_src, B1, dinv, b2, B0, N, 1);

    // Layer 3: B0 -> HS=B0 (alias-safe) -> X3=B1 (no relu)
    k_gemm<<<gGemm, T, 0, stream>>>(B0, whi3, wlo3, dinv, B0, N);
    k_gather<<<gGather, T, 0, stream>>>(rowptr, csr_src, B0, dinv, b3, B1, N, 0);

    // Two-stage pool + fused final linear (psum aliases B0, now dead)
    k_pool_part<<<G * QSEG, 128, 0, stream>>>(B1, batch, psum, N);
    k_pool_final<<<G, 128, 0, stream>>>(psum, batch, Wl, bl, out, N, C);
}